// Round 1
// baseline (984.644 us; speedup 1.0000x reference)
//
#include <hip/hip_runtime.h>
#include <math.h>

// Problem: single-head causal attention.
//   x:[8,2048,1024] f32, Wq/Wk/Wv:[1024,64] f32, zero_mask:[8,2048] int
//   out:[8,2048,64] f32
// Round 0: correct fp32 baseline. QKV GEMM kernel + flash-style attention
// (no max-subtraction: scores ~N(0,0.1^2), exp overflow impossible).

#define B_ 8
#define C_ 2048
#define E_ 1024
#define H_ 64

// ---------------------------------------------------------------------------
// QKV projection: q/k/v[row][h] = sum_e x[row][e] * W[e][h]
// 512 blocks x 256 threads; 32 rows per block; x chunk staged in LDS
// (stride 65 to avoid bank conflicts); W read from global (L1/L2-resident,
// 16-lane broadcast). Thread tile: 2 rows x 4 h x 3 matrices = 24 acc.
// ---------------------------------------------------------------------------
__global__ __launch_bounds__(256, 2) void qkv_kernel(
    const float* __restrict__ X,
    const float* __restrict__ Wq,
    const float* __restrict__ Wk,
    const float* __restrict__ Wv,
    float* __restrict__ q_ws,
    float* __restrict__ k_ws,
    float* __restrict__ v_ws)
{
    __shared__ float xs[32 * 65];
    const int tid = (int)threadIdx.x;
    const int r0  = (int)blockIdx.x * 32;
    const int rg  = tid & 15;   // row group: local rows rg*2, rg*2+1
    const int hg  = tid >> 4;   // h group: h = hg*4 .. +3

    float acc[3][2][4];
#pragma unroll
    for (int m = 0; m < 3; m++)
#pragma unroll
        for (int i = 0; i < 2; i++)
#pragma unroll
            for (int j = 0; j < 4; j++) acc[m][i][j] = 0.f;

    for (int k0 = 0; k0 < E_; k0 += 64) {
        __syncthreads();
        // stage 32 rows x 64 k of x (2048 floats; 2 float4 per thread)
#pragma unroll
        for (int j = 0; j < 2; j++) {
            int idx = tid + j * 256;   // float4 index 0..511
            int row = idx >> 4;        // 0..31
            int e4  = idx & 15;        // 0..15
            float4 xv = *(const float4*)(X + (size_t)(r0 + row) * E_ + k0 + e4 * 4);
            float* d = &xs[row * 65 + e4 * 4];
            d[0] = xv.x; d[1] = xv.y; d[2] = xv.z; d[3] = xv.w;
        }
        __syncthreads();

#pragma unroll 8
        for (int kk = 0; kk < 64; kk++) {
            const int k = k0 + kk;
            float xx[2];
            xx[0] = xs[(rg * 2 + 0) * 65 + kk];
            xx[1] = xs[(rg * 2 + 1) * 65 + kk];
            float4 w4[3];
            w4[0] = *(const float4*)(Wq + (size_t)k * H_ + hg * 4);
            w4[1] = *(const float4*)(Wk + (size_t)k * H_ + hg * 4);
            w4[2] = *(const float4*)(Wv + (size_t)k * H_ + hg * 4);
#pragma unroll
            for (int m = 0; m < 3; m++) {
                const float* w = (const float*)&w4[m];
#pragma unroll
                for (int i = 0; i < 2; i++)
#pragma unroll
                    for (int j = 0; j < 4; j++)
                        acc[m][i][j] += xx[i] * w[j];
            }
        }
    }

#pragma unroll
    for (int i = 0; i < 2; i++) {
        const size_t o = (size_t)(r0 + rg * 2 + i) * H_ + hg * 4;
        *(float4*)(q_ws + o) = make_float4(acc[0][i][0], acc[0][i][1], acc[0][i][2], acc[0][i][3]);
        *(float4*)(k_ws + o) = make_float4(acc[1][i][0], acc[1][i][1], acc[1][i][2], acc[1][i][3]);
        *(float4*)(v_ws + o) = make_float4(acc[2][i][0], acc[2][i][1], acc[2][i][2], acc[2][i][3]);
    }
}

// ---------------------------------------------------------------------------
// Flash-style causal attention (no max subtraction; scores are tiny).
// Grid (8 batches = x, 64 qtiles = y remapped for causal load balance).
// Block: 256 threads; 32 q-rows; thread (r = tid>>3, p = tid&7) owns q-row r
// (in registers, pre-scaled), 8 score cols c = 8j+p (bank-conflict-free K
// reads), and 8 output h = p*8..+7. P broadcast within the row's 8 lanes via
// __shfl. K/V 64-key tiles staged in LDS with pad 68.
// ---------------------------------------------------------------------------
__global__ __launch_bounds__(256, 2) void attn_kernel(
    const float* __restrict__ q_ws,
    const float* __restrict__ k_ws,
    const float* __restrict__ v_ws,
    const int*  __restrict__ zmask,
    float* __restrict__ out)
{
    __shared__ float Ks[64 * 68];
    __shared__ float Vs[64 * 68];

    const int tid = (int)threadIdx.x;
    const int b   = (int)blockIdx.x;                 // batch (XCD affinity)
    const int y   = (int)blockIdx.y;                 // 0..63
    const int qt  = (y < 32) ? y : (95 - y);         // causal load-balance remap
    const int q0  = qt * 32;
    const int r   = tid >> 3;                        // local q row 0..31
    const int p   = tid & 7;
    const int row = q0 + r;                          // global q row in batch

    const float scale = 0.02209708691207961f;        // 2048^-0.5

    // q row into registers, pre-scaled
    float4 q4[16];
    const float4* qrow = (const float4*)(q_ws + ((size_t)b * C_ + row) * H_);
#pragma unroll
    for (int e = 0; e < 16; e++) {
        float4 t = qrow[e];
        t.x *= scale; t.y *= scale; t.z *= scale; t.w *= scale;
        q4[e] = t;
    }

    float O[8];
#pragma unroll
    for (int j = 0; j < 8; j++) O[j] = 0.f;
    float l = 0.f;

    const int nkt = (q0 + 95) >> 6;   // key tiles needed to cover key <= q0+31
    for (int kt = 0; kt < nkt; kt++) {
        const int k0 = kt * 64;
        __syncthreads();
        // stage K,V tile: 64 keys x 64 h (4 float4 per thread per matrix)
#pragma unroll
        for (int j = 0; j < 4; j++) {
            int idx = tid + j * 256;   // 0..1023
            int kr  = idx >> 4;        // 0..63
            int e4  = idx & 15;
            const size_t g = ((size_t)b * C_ + k0 + kr) * H_ + e4 * 4;
            float4 kv = *(const float4*)(k_ws + g);
            float4 vv = *(const float4*)(v_ws + g);
            *(float4*)&Ks[kr * 68 + e4 * 4] = kv;
            *(float4*)&Vs[kr * 68 + e4 * 4] = vv;
        }
        __syncthreads();

        // S = q . K^T for this thread's 8 cols (c = 8j + p), then exp
        float pexp[8];
#pragma unroll
        for (int j = 0; j < 8; j++) {
            const int c = j * 8 + p;
            const float4* kc = (const float4*)&Ks[c * 68];
            float a0 = 0.f, a1 = 0.f, a2 = 0.f, a3 = 0.f;
#pragma unroll
            for (int e = 0; e < 16; e++) {
                float4 kk = kc[e];
                a0 += q4[e].x * kk.x;
                a1 += q4[e].y * kk.y;
                a2 += q4[e].z * kk.z;
                a3 += q4[e].w * kk.w;
            }
            const float s = (a0 + a1) + (a2 + a3);
            const int key = k0 + c;
            const float pe = (key <= row) ? __expf(s) : 0.f;
            pexp[j] = pe;
            l += pe;
        }

        // O[h] += sum_c P[r][c] * V[c][h]  (P fetched from the row's lanes)
        const int lbase = tid & 56;   // lane bits of r within the wave
#pragma unroll 16
        for (int c = 0; c < 64; c++) {
            const float pc = __shfl(pexp[c >> 3], lbase | (c & 7), 64);
            const float4* vc = (const float4*)&Vs[c * 68 + p * 8];
            const float4 v0 = vc[0];
            const float4 v1 = vc[1];
            O[0] += pc * v0.x; O[1] += pc * v0.y; O[2] += pc * v0.z; O[3] += pc * v0.w;
            O[4] += pc * v1.x; O[5] += pc * v1.y; O[6] += pc * v1.z; O[7] += pc * v1.w;
        }
    }

    // row softmax denominator: reduce partial l over the row's 8 lanes
    l += __shfl_xor(l, 1, 64);
    l += __shfl_xor(l, 2, 64);
    l += __shfl_xor(l, 4, 64);
    const float inv = 1.0f / l;

    const int zm = zmask[b * C_ + row];   // post-softmax row zeroing
    float4 o0, o1;
    if (zm != 0) {
        o0 = make_float4(0.f, 0.f, 0.f, 0.f);
        o1 = o0;
    } else {
        o0 = make_float4(O[0] * inv, O[1] * inv, O[2] * inv, O[3] * inv);
        o1 = make_float4(O[4] * inv, O[5] * inv, O[6] * inv, O[7] * inv);
    }
    float4* op = (float4*)(out + ((size_t)b * C_ + row) * H_ + (size_t)p * 8);
    op[0] = o0;
    op[1] = o1;
}

// ---------------------------------------------------------------------------
extern "C" void kernel_launch(void* const* d_in, const int* in_sizes, int n_in,
                              void* d_out, int out_size, void* d_ws, size_t ws_size,
                              hipStream_t stream) {
    const float* X  = (const float*)d_in[0];
    const float* Wq = (const float*)d_in[1];
    const float* Wk = (const float*)d_in[2];
    const float* Wv = (const float*)d_in[3];
    const int*   zm = (const int*)d_in[4];
    float* out = (float*)d_out;

    float* q_ws = (float*)d_ws;                       // 16384*64 f32 = 4 MB
    float* k_ws = q_ws + (size_t)B_ * C_ * H_;        // 4 MB
    float* v_ws = k_ws + (size_t)B_ * C_ * H_;        // 4 MB (12 MB total)

    qkv_kernel<<<dim3((B_ * C_) / 32), dim3(256), 0, stream>>>(
        X, Wq, Wk, Wv, q_ws, k_ws, v_ws);

    attn_kernel<<<dim3(B_, 64), dim3(256), 0, stream>>>(
        q_ws, k_ws, v_ws, zm, out);
}

// Round 2
// 231.466 us; speedup vs baseline: 4.2539x; 4.2539x over previous
//
#include <hip/hip_runtime.h>
#include <math.h>

// Single-head causal attention, MFMA bf16 pipeline.
//   x:[8,2048,1024] f32, Wq/Wk/Wv:[1024,64] f32, zero_mask:[8,2048] i32
//   out:[8,2048,64] f32
// Stage 1: wcvt  -> Wt[192][1024] bf16 (transposed, B-operand layout)
// Stage 2: qkv   -> Q (pre-scaled), K as [row][64] bf16; V transposed [h][key] bf16
// Stage 3: attn  -> flash-style causal, 16x16x32 bf16 MFMA, no max-subtraction
//
// MFMA 16x16x32 layouts (per guide, HW-verified):
//   A[m][k]: m = lane&15, k = (lane>>4)*8 + j   (j = elt 0..7 of short8)
//   B[k][n]: n = lane&15, k = (lane>>4)*8 + j
//   C/D:     col = lane&15, row = (lane>>4)*4 + reg

#define B_ 8
#define C_ 2048
#define E_ 1024
#define H_ 64
#define SCALE 0.02209708691207961f  // 2048^-0.5

typedef __attribute__((ext_vector_type(8))) short short8;
typedef __attribute__((ext_vector_type(4))) float floatx4;

union BF8 { short8 s8; unsigned int u[4]; };

static __device__ __forceinline__ unsigned int pack_bf2(float lo, float hi) {
    // two fp32 -> bf16 pair (truncation; bias cancels in softmax, tiny vs thresh)
    unsigned int a = __builtin_bit_cast(unsigned int, lo);
    unsigned int b = __builtin_bit_cast(unsigned int, hi);
    return (a >> 16) | (b & 0xFFFF0000u);
}
static __device__ __forceinline__ unsigned short f2bf(float f) {
    return (unsigned short)(__builtin_bit_cast(unsigned int, f) >> 16);
}

// ---------------------------------------------------------------------------
// Wt[n=192][k=1024] bf16 from Wq/Wk/Wv[k=1024][h=64] f32. 48 blocks.
// ---------------------------------------------------------------------------
__global__ __launch_bounds__(256) void wcvt_kernel(
    const float* __restrict__ Wq, const float* __restrict__ Wk,
    const float* __restrict__ Wv, unsigned short* __restrict__ wt)
{
    __shared__ float lds[64][68];
    const int bid = (int)blockIdx.x;
    const int m = bid >> 4, kt = bid & 15, k0 = kt * 64;
    const float* W = (m == 0) ? Wq : (m == 1) ? Wk : Wv;
    const int t = (int)threadIdx.x;
#pragma unroll
    for (int j = 0; j < 4; j++) {
        int idx4 = j * 256 + t;           // 1024 float4
        int row = idx4 >> 4, c4 = idx4 & 15;
        float4 v = *(const float4*)(W + (size_t)(k0 + row) * 64 + c4 * 4);
        *(float4*)&lds[row][c4 * 4] = v;
    }
    __syncthreads();
#pragma unroll
    for (int j = 0; j < 2; j++) {
        int g = j * 256 + t;              // 512 16B-granules
        int n = g >> 3, kk = (g & 7) * 8;
        unsigned int o[4];
#pragma unroll
        for (int i = 0; i < 4; i++)
            o[i] = pack_bf2(lds[kk + 2 * i][n], lds[kk + 2 * i + 1][n]);
        *(uint4*)(wt + (size_t)(m * 64 + n) * 1024 + k0 + kk) =
            make_uint4(o[0], o[1], o[2], o[3]);
    }
}

// ---------------------------------------------------------------------------
// QKV MFMA GEMM: M=16384, N=192, K=1024. 256 blocks x 256 thr (4 waves).
// Wave = 32 rows x 96 cols: msub in {0,1}, 6 n-tiles. Wt chunk in LDS.
// ---------------------------------------------------------------------------
__global__ __launch_bounds__(256, 3) void qkv_kernel(
    const float* __restrict__ X, const unsigned short* __restrict__ wt,
    unsigned short* __restrict__ qg, unsigned short* __restrict__ kg,
    unsigned short* __restrict__ vtg)
{
    __shared__ unsigned short wlds[192 * 72];   // [n][k64 + pad], 144B rows
    const int t = (int)threadIdx.x;
    const int wv = t >> 6, lane = t & 63;
    const int l15 = lane & 15, quad = lane >> 4;
    const int r0 = (int)blockIdx.x * 64;
    const int m0 = (wv & 1) * 32;       // wave row offset
    const int n0 = (wv >> 1) * 96;      // wave col offset

    floatx4 acc[2][6];
#pragma unroll
    for (int i = 0; i < 2; i++)
#pragma unroll
        for (int j = 0; j < 6; j++) acc[i][j] = (floatx4){0.f, 0.f, 0.f, 0.f};

    for (int k0 = 0; k0 < E_; k0 += 64) {
        // prefetch A (X fp32) and W-chunk into regs before the barrier
        float4 areg[2][2][2];   // [msub][kc][half]
#pragma unroll
        for (int ms = 0; ms < 2; ms++)
#pragma unroll
            for (int kc = 0; kc < 2; kc++) {
                const float* p = X + (size_t)(r0 + m0 + ms * 16 + l15) * E_
                                 + k0 + kc * 32 + quad * 8;
                areg[ms][kc][0] = *(const float4*)p;
                areg[ms][kc][1] = *(const float4*)(p + 4);
            }
        uint4 wreg[6];
#pragma unroll
        for (int j = 0; j < 6; j++) {
            int g = j * 256 + t;          // 1536 granules: 192 rows x 8
            int n = g >> 3, gk = g & 7;
            wreg[j] = *(const uint4*)(wt + (size_t)n * 1024 + k0 + gk * 8);
        }
        __syncthreads();
#pragma unroll
        for (int j = 0; j < 6; j++) {
            int g = j * 256 + t;
            int n = g >> 3, gk = g & 7;
            *(uint4*)&wlds[n * 72 + gk * 8] = wreg[j];
        }
        __syncthreads();

        // pack A to bf16 frags
        short8 afr[2][2];
#pragma unroll
        for (int ms = 0; ms < 2; ms++)
#pragma unroll
            for (int kc = 0; kc < 2; kc++) {
                BF8 u;
                float4 f0 = areg[ms][kc][0], f1 = areg[ms][kc][1];
                u.u[0] = pack_bf2(f0.x, f0.y);
                u.u[1] = pack_bf2(f0.z, f0.w);
                u.u[2] = pack_bf2(f1.x, f1.y);
                u.u[3] = pack_bf2(f1.z, f1.w);
                afr[ms][kc] = u.s8;
            }
#pragma unroll
        for (int kc = 0; kc < 2; kc++)
#pragma unroll
            for (int nt = 0; nt < 6; nt++) {
                short8 bfr = *(const short8*)&wlds[(n0 + nt * 16 + l15) * 72
                                                  + kc * 32 + quad * 8];
#pragma unroll
                for (int ms = 0; ms < 2; ms++)
                    acc[ms][nt] = __builtin_amdgcn_mfma_f32_16x16x32_bf16(
                        afr[ms][kc], bfr, acc[ms][nt], 0, 0, 0);
            }
    }

    // epilogue: C/D row = quad*4+reg, col = l15
    const int bb = r0 >> 11;            // batch
    const int keybase = r0 & 2047;
#pragma unroll
    for (int ms = 0; ms < 2; ms++)
#pragma unroll
        for (int nt = 0; nt < 6; nt++) {
            const int c = n0 + nt * 16 + l15;
            const int rowl = m0 + ms * 16 + quad * 4;
            if (c < 64) {               // Q, pre-scaled
#pragma unroll
                for (int r = 0; r < 4; r++)
                    qg[(size_t)(r0 + rowl + r) * 64 + c] =
                        f2bf(acc[ms][nt][r] * SCALE);
            } else if (c < 128) {       // K
#pragma unroll
                for (int r = 0; r < 4; r++)
                    kg[(size_t)(r0 + rowl + r) * 64 + (c - 64)] =
                        f2bf(acc[ms][nt][r]);
            } else {                    // V transposed: Vt[b][h][key]
                const int h = c - 128;
                unsigned int p0 = pack_bf2(acc[ms][nt][0], acc[ms][nt][1]);
                unsigned int p1 = pack_bf2(acc[ms][nt][2], acc[ms][nt][3]);
                *(uint2*)(vtg + (size_t)(bb * 64 + h) * 2048 + keybase + rowl) =
                    make_uint2(p0, p1);
            }
        }
}

// ---------------------------------------------------------------------------
// Flash-style causal attention, MFMA. Grid (8, 64) remapped; 128 thr (2 waves);
// 32 q-rows per block, wave owns a 16-row m-tile (no cross-wave coupling).
// ---------------------------------------------------------------------------
__global__ __launch_bounds__(128, 3) void attn_kernel(
    const unsigned short* __restrict__ qg, const unsigned short* __restrict__ kg,
    const unsigned short* __restrict__ vtg, const int* __restrict__ zmask,
    float* __restrict__ out)
{
    __shared__ unsigned short Klds[64 * 72];   // [key][h + pad]
    __shared__ unsigned short Vlds[64 * 72];   // [h][key + pad]
    __shared__ unsigned short Ps[2 * 16 * 72]; // per-wave P tile [q16][key64+pad]

    const int t = (int)threadIdx.x;
    const int wv = t >> 6, lane = t & 63;
    const int l15 = lane & 15, quad = lane >> 4;
    const int b = (int)blockIdx.x;
    const int y = (int)blockIdx.y;
    const int qt = (y < 32) ? y : (95 - y);    // causal load-balance remap
    const int q0 = qt * 32;
    const int qrow_lo = q0 + wv * 16;
    const int myrow = qrow_lo + quad * 4;      // + reg (C layout)

    // Q A-frags (held whole kernel); scale pre-folded in qkv
    short8 qfr[2];
#pragma unroll
    for (int kc = 0; kc < 2; kc++)
        qfr[kc] = *(const short8*)(qg + (size_t)(b * C_ + qrow_lo + l15) * 64
                                   + kc * 32 + quad * 8);

    floatx4 accO[4];
#pragma unroll
    for (int i = 0; i < 4; i++) accO[i] = (floatx4){0.f, 0.f, 0.f, 0.f};
    float lsum[4] = {0.f, 0.f, 0.f, 0.f};

    const int nkt = (q0 + 95) >> 6;
    for (int kt = 0; kt < nkt; kt++) {
        const int k0 = kt * 64;
        uint4 kreg[4], vreg[4];
#pragma unroll
        for (int j = 0; j < 4; j++) {
            int g = j * 128 + t;        // 512 granules: 64 rows x 8
            int row = g >> 3, gk = g & 7;
            kreg[j] = *(const uint4*)(kg + (size_t)(b * C_ + k0 + row) * 64 + gk * 8);
            vreg[j] = *(const uint4*)(vtg + (size_t)(b * 64 + row) * 2048 + k0 + gk * 8);
        }
        __syncthreads();
#pragma unroll
        for (int j = 0; j < 4; j++) {
            int g = j * 128 + t;
            int row = g >> 3, gk = g & 7;
            *(uint4*)&Klds[row * 72 + gk * 8] = kreg[j];
            *(uint4*)&Vlds[row * 72 + gk * 8] = vreg[j];
        }
        __syncthreads();

        // S = Q K^T (4 key-tiles of 16)
        floatx4 s[4];
#pragma unroll
        for (int nt = 0; nt < 4; nt++) {
            short8 kf0 = *(const short8*)&Klds[(nt * 16 + l15) * 72 + quad * 8];
            short8 kf1 = *(const short8*)&Klds[(nt * 16 + l15) * 72 + 32 + quad * 8];
            floatx4 z = (floatx4){0.f, 0.f, 0.f, 0.f};
            z = __builtin_amdgcn_mfma_f32_16x16x32_bf16(qfr[0], kf0, z, 0, 0, 0);
            s[nt] = __builtin_amdgcn_mfma_f32_16x16x32_bf16(qfr[1], kf1, z, 0, 0, 0);
        }
        // P = exp(s) with causal mask; accumulate row sums; stage P (bf16)
#pragma unroll
        for (int nt = 0; nt < 4; nt++) {
            const int key = k0 + nt * 16 + l15;
#pragma unroll
            for (int r = 0; r < 4; r++) {
                float p = (key <= myrow + r) ? __expf(s[nt][r]) : 0.f;
                lsum[r] += p;
                Ps[(wv * 16 + quad * 4 + r) * 72 + nt * 16 + l15] = f2bf(p);
            }
        }
        // O += P V   (P: LDS C-layout -> A-layout; V^T already B-layout)
#pragma unroll
        for (int kc2 = 0; kc2 < 2; kc2++) {
            short8 af = *(const short8*)&Ps[(wv * 16 + l15) * 72 + kc2 * 32 + quad * 8];
#pragma unroll
            for (int nt = 0; nt < 4; nt++) {
                short8 vf = *(const short8*)&Vlds[(nt * 16 + l15) * 72
                                                 + kc2 * 32 + quad * 8];
                accO[nt] = __builtin_amdgcn_mfma_f32_16x16x32_bf16(
                    af, vf, accO[nt], 0, 0, 0);
            }
        }
    }

    // row sums: reduce across the 16-lane col group
#pragma unroll
    for (int r = 0; r < 4; r++) {
        float v = lsum[r];
        v += __shfl_xor(v, 1);
        v += __shfl_xor(v, 2);
        v += __shfl_xor(v, 4);
        v += __shfl_xor(v, 8);
        lsum[r] = v;
    }
    float inv[4];
#pragma unroll
    for (int r = 0; r < 4; r++) {
        int zm = zmask[b * C_ + myrow + r];
        inv[r] = zm ? 0.f : 1.0f / lsum[r];
    }
#pragma unroll
    for (int nt = 0; nt < 4; nt++)
#pragma unroll
        for (int r = 0; r < 4; r++)
            out[(size_t)(b * C_ + myrow + r) * 64 + nt * 16 + l15] =
                accO[nt][r] * inv[r];
}

// ---------------------------------------------------------------------------
extern "C" void kernel_launch(void* const* d_in, const int* in_sizes, int n_in,
                              void* d_out, int out_size, void* d_ws, size_t ws_size,
                              hipStream_t stream) {
    const float* X  = (const float*)d_in[0];
    const float* Wq = (const float*)d_in[1];
    const float* Wk = (const float*)d_in[2];
    const float* Wv = (const float*)d_in[3];
    const int*   zm = (const int*)d_in[4];
    float* out = (float*)d_out;

    // workspace (bf16 = unsigned short):
    unsigned short* qg  = (unsigned short*)d_ws;                 // 2 MB
    unsigned short* kg  = qg  + (size_t)B_ * C_ * H_;            // 2 MB
    unsigned short* vtg = kg  + (size_t)B_ * C_ * H_;            // 2 MB, [b][h][key]
    unsigned short* wt  = vtg + (size_t)B_ * C_ * H_;            // 384 KB, [192][1024]

    wcvt_kernel<<<dim3(48), dim3(256), 0, stream>>>(Wq, Wk, Wv, wt);
    qkv_kernel<<<dim3(256), dim3(256), 0, stream>>>(X, wt, qg, kg, vtg);
    attn_kernel<<<dim3(B_, 64), dim3(128), 0, stream>>>(qg, kg, vtg, zm, out);
}